// Round 4
// baseline (2454.076 us; speedup 1.0000x reference)
//
#include <hip/hip_runtime.h>
#include <hip/hip_bf16.h>

#define LNUM 128
#define NNODES 30000
#define NEDGES 150000
#define NSTEPS 5

// NOTE (r17 discovery): d_out is FLOAT32 (reference is pure jnp.float32).
// Split-f16 numerics: x = hi + lo/2048 -> 3 MFMAs per frag pair, ~f32 accuracy.
// r3 post-mortem: swapped-orientation epilogue (LDS bounce + regrouped atomics)
// gave scheduling-dependent absmax 0.035-0.0625 -> FAILED. r4: NON-swapped
// mfma(X,W) reuses round-1's twice-verified D-layout/epilogue (direct coalesced
// writes, full-line atomics), keeps r3's zero-barrier reg-gather + direct
// weight loads. LDS only for wave-private packed Y (33.8KB, no barriers).

typedef _Float16 f16;
typedef __attribute__((ext_vector_type(8))) _Float16 f16x8;
typedef __attribute__((ext_vector_type(4))) float f32x4;

__device__ __forceinline__ uint32_t pk2(f16 a, f16 b) {
    union { f16 h[2]; uint32_t u; } x; x.h[0] = a; x.h[1] = b; return x.u;
}

// ---------------------------------------------------------------------------
// Legacy VALU MLP core: still used by the (small) encode_nodes kernel.
// ---------------------------------------------------------------------------
template<int ROWS, int K, int KP>
__device__ __forceinline__ void mlp_apply(
    const float* __restrict__ xs, float* __restrict__ hv,
    float* __restrict__ mu_s, float* __restrict__ rs_s,
    const float* __restrict__ W1, const float* __restrict__ b1,
    const float* __restrict__ W2, const float* __restrict__ b2,
    const float* __restrict__ g,  const float* __restrict__ be,
    float out[ROWS])
{
    const int t = threadIdx.x;
    float acc[ROWS];
    {
        const float bb = b1[t];
        #pragma unroll
        for (int r = 0; r < ROWS; r++) acc[r] = bb;
    }
    int k = 0;
    for (; k + 4 <= K; k += 4) {
        const float w0 = W1[(k + 0) * LNUM + t];
        const float w1 = W1[(k + 1) * LNUM + t];
        const float w2 = W1[(k + 2) * LNUM + t];
        const float w3 = W1[(k + 3) * LNUM + t];
        #pragma unroll
        for (int r = 0; r < ROWS; r++) {
            const float4 x = *(const float4*)(xs + r * KP + k);
            acc[r] = fmaf(x.x, w0, acc[r]);
            acc[r] = fmaf(x.y, w1, acc[r]);
            acc[r] = fmaf(x.z, w2, acc[r]);
            acc[r] = fmaf(x.w, w3, acc[r]);
        }
    }
    for (; k < K; ++k) {
        const float w = W1[k * LNUM + t];
        #pragma unroll
        for (int r = 0; r < ROWS; r++) acc[r] = fmaf(xs[r * KP + k], w, acc[r]);
    }
    #pragma unroll
    for (int r = 0; r < ROWS; r++) hv[r * LNUM + t] = fmaxf(acc[r], 0.f);
    __syncthreads();
    {
        const float bb = b2[t];
        #pragma unroll
        for (int r = 0; r < ROWS; r++) acc[r] = bb;
    }
    for (int k2 = 0; k2 < LNUM; k2 += 4) {
        const float w0 = W2[(k2 + 0) * LNUM + t];
        const float w1 = W2[(k2 + 1) * LNUM + t];
        const float w2 = W2[(k2 + 2) * LNUM + t];
        const float w3 = W2[(k2 + 3) * LNUM + t];
        #pragma unroll
        for (int r = 0; r < ROWS; r++) {
            const float4 x = *(const float4*)(hv + r * LNUM + k2);
            acc[r] = fmaf(x.x, w0, acc[r]);
            acc[r] = fmaf(x.y, w1, acc[r]);
            acc[r] = fmaf(x.z, w2, acc[r]);
            acc[r] = fmaf(x.w, w3, acc[r]);
        }
    }
    __syncthreads();
    #pragma unroll
    for (int r = 0; r < ROWS; r++) hv[r * LNUM + t] = fmaxf(acc[r], 0.f);
    __syncthreads();
    if (t < ROWS) {
        float s = 0.f, s2 = 0.f;
        for (int kk = 0; kk < LNUM; kk++) {
            const float v = hv[t * LNUM + kk];
            s += v; s2 += v * v;
        }
        const float m = s * (1.0f / LNUM);
        mu_s[t] = m;
        rs_s[t] = rsqrtf(fmaxf(s2 * (1.0f / LNUM) - m * m, 0.f) + 1e-5f);
    }
    __syncthreads();
    const float gg = g[t], bbe = be[t];
    #pragma unroll
    for (int r = 0; r < ROWS; r++)
        out[r] = fmaf(gg * (hv[r * LNUM + t] - mu_s[r]), rs_s[r], bbe);
}

__global__ __launch_bounds__(128) void encode_nodes_k(
    const float* __restrict__ u, const float* __restrict__ load_,
    const float* __restrict__ ntype,
    const float* __restrict__ W1, const float* __restrict__ b1,
    const float* __restrict__ W2, const float* __restrict__ b2,
    const float* __restrict__ g,  const float* __restrict__ be,
    float* __restrict__ nl)
{
    constexpr int ROWS = 4, K = 12, KP = 12;
    __shared__ __align__(16) float xs[ROWS * KP];
    __shared__ __align__(16) float hv[ROWS * LNUM];
    __shared__ float mu_s[ROWS], rs_s[ROWS];
    const int t = threadIdx.x;
    const int base = blockIdx.x * ROWS;
    if (t < ROWS * K) {
        const int r = t / K, k = t % K;
        const int n = base + r;
        float v;
        if (k < 2)      v = u[n * 2 + k];
        else if (k < 3) v = load_[n];
        else            v = ntype[n * 9 + (k - 3)];
        xs[r * KP + k] = v;
    }
    __syncthreads();
    float out[ROWS];
    mlp_apply<ROWS, K, KP>(xs, hv, mu_s, rs_s, W1, b1, W2, b2, g, be, out);
    #pragma unroll
    for (int r = 0; r < ROWS; r++) nl[(base + r) * LNUM + t] = out[r];
}

// ---------------------------------------------------------------------------
// Weight prep: f32 [S][K][128] -> f16 hi/lo tables transposed to [S][128][K].
// ---------------------------------------------------------------------------
#define PE1 245760   // 5*384*128 (edge W1)
#define PE2 81920    // 5*128*128 (edge W2)
#define PN1 163840   // 5*256*128 (node W1)
#define PN2 81920    // 5*128*128 (node W2)
#define PQ1 4096     // 128*32    (enc-edge W1, k-padded)
#define PQ2 16384    // 128*128   (enc-edge W2)
#define PTOT (PE1+PE2+PN1+PN2+PQ1+PQ2)

__global__ __launch_bounds__(256) void prep_w_all_k(
    const float* __restrict__ eW1, const float* __restrict__ eW2,
    const float* __restrict__ nW1, const float* __restrict__ nW2,
    const float* __restrict__ qW1, const float* __restrict__ qW2,
    f16* __restrict__ out)
{
    int j = blockIdx.x * 256 + threadIdx.x;
    if (j >= PTOT) return;
    const float* W; int K, kreal; f16 *hi, *lo; f16* p = out;
    if (j < PE1) { W = eW1; K = 384; kreal = 384; hi = p; lo = p + PE1; }
    else { p += 2 * PE1; j -= PE1;
    if (j < PE2) { W = eW2; K = 128; kreal = 128; hi = p; lo = p + PE2; }
    else { p += 2 * PE2; j -= PE2;
    if (j < PN1) { W = nW1; K = 256; kreal = 256; hi = p; lo = p + PN1; }
    else { p += 2 * PN1; j -= PN1;
    if (j < PN2) { W = nW2; K = 128; kreal = 128; hi = p; lo = p + PN2; }
    else { p += 2 * PN2; j -= PN2;
    if (j < PQ1) { W = qW1; K = 32;  kreal = 5;   hi = p; lo = p + PQ1; }
    else { p += 2 * PQ1; j -= PQ1;
         { W = qW2; K = 128; kreal = 128; hi = p; lo = p + PQ2; } } } } } }
    const int k = j % K;
    const int rem = j / K;
    const int n = rem & 127;
    const int s = rem >> 7;
    const float v = (k < kreal) ? W[((size_t)s * kreal + k) * 128 + n] : 0.f;
    const f16 h = (f16)v;
    hi[j] = h;
    lo[j] = (f16)((v - (float)h) * 2048.f);
}

// ---------------------------------------------------------------------------
// Barrier-free NON-swapped MFMA MLP. 256 threads = 4 waves, 64 rows/block.
// A = data gathered per-lane into regs (lane (lg,lr) holds row w*16+lr,
// k = kc*32+lg*8..+8). B = W^T rows loaded directly global->VGPR
// (lane holds W[n=mf*16+lr][k=lg*8..+8]; L1-broadcast across waves/blocks).
// D layout (round-1 verified): edge = w*16 + lg*4 + reg, feature = mf*16 + lr
// -> epilogue writes/atomics are 16-consecutive-col (full 64B lines).
// Layer1->2 transpose via packed wave-private LDS Y (no barriers anywhere).
// MODE: 0 = edge block, 1 = node block, 2 = edge encoder.
// ---------------------------------------------------------------------------
template<int MODE, int NCH1, int K1S>
__global__ __launch_bounds__(256) void mfma_mlp_k(
    const float* __restrict__ in0, const float* __restrict__ in1,
    float* __restrict__ io, float* __restrict__ aggr,
    const int* __restrict__ senders, const int* __restrict__ receivers,
    const f16* __restrict__ W1h, const f16* __restrict__ W1l, const float* __restrict__ b1,
    const f16* __restrict__ W2h, const f16* __restrict__ W2l, const float* __restrict__ b2,
    const float* __restrict__ gam, const float* __restrict__ bet,
    int nrows)
{
    __shared__ __align__(16) uint32_t Yp[64 * 132];   // packed hi|lo, 33.8 KB

    const int t  = threadIdx.x;
    const int w  = t >> 6;
    const int l  = t & 63;
    const int lr = l & 15;
    const int lg = l >> 4;
    const int base = blockIdx.x * 64;

    const int eg  = base + w * 16 + lr;    // this lane's gather row (A-row)
    const int egc = min(eg, nrows - 1);

    int sv = 0, rv = 0;
    if constexpr (MODE != 1) { sv = senders[egc]; rv = receivers[egc]; }

    float feat[8];
    if constexpr (MODE == 2) {
        const float ax = in0[sv * 2], ay = in0[sv * 2 + 1];
        const float bx = in0[rv * 2], by = in0[rv * 2 + 1];
        const float rx = ax - bx, ry = ay - by;
        feat[0] = rx; feat[1] = ry; feat[2] = sqrtf(rx * rx + ry * ry);
        feat[3] = in1[sv * 2] - in1[rv * 2];
        feat[4] = in1[sv * 2 + 1] - in1[rv * 2 + 1];
        feat[5] = 0.f; feat[6] = 0.f; feat[7] = 0.f;
    }

    const f32x4 zero4 = {0.f, 0.f, 0.f, 0.f};
    f32x4 accH[8], accL[8];
    #pragma unroll
    for (int mf = 0; mf < 8; mf++) { accH[mf] = zero4; accL[mf] = zero4; }

    // ---------------- layer 1 (no barriers) ----------------
    for (int kc = 0; kc < NCH1; ++kc) {
        union { f16 h[8]; f16x8 v; } XH, XL;
        if constexpr (MODE == 2) {
            #pragma unroll
            for (int j = 0; j < 8; j++) {
                const float x = (lg == 0) ? feat[j] : 0.f;
                const f16 h = (f16)x;
                XH.h[j] = h;
                XL.h[j] = (f16)((x - (float)h) * 2048.f);
            }
        } else {
            const float* src;
            if constexpr (MODE == 0) {
                if (kc < 4)      src = in0 + (size_t)sv  * 128 + kc * 32 + lg * 8;
                else if (kc < 8) src = in0 + (size_t)rv  * 128 + (kc - 4) * 32 + lg * 8;
                else             src = in1 + (size_t)egc * 128 + (kc - 8) * 32 + lg * 8;
            } else {
                if (kc < 4) src = in0 + (size_t)egc * 128 + kc * 32 + lg * 8;
                else        src = in1 + (size_t)egc * 128 + (kc - 4) * 32 + lg * 8;
            }
            const float4 x0 = *(const float4*)src;
            const float4 x1 = *(const float4*)(src + 4);
            const float xv[8] = {x0.x, x0.y, x0.z, x0.w, x1.x, x1.y, x1.z, x1.w};
            #pragma unroll
            for (int j = 0; j < 8; j++) {
                const f16 h = (f16)xv[j];
                XH.h[j] = h;
                XL.h[j] = (f16)((xv[j] - (float)h) * 2048.f);
            }
        }
        #pragma unroll
        for (int mf = 0; mf < 8; mf++) {
            const size_t ro = (size_t)(mf * 16 + lr) * K1S + kc * 32 + lg * 8;
            const f16x8 wh = *(const f16x8*)(W1h + ro);
            const f16x8 wl = *(const f16x8*)(W1l + ro);
            // NON-swapped: A = data, B = weights (round-1 verified D layout)
            accH[mf] = __builtin_amdgcn_mfma_f32_16x16x32_f16(XH.v, wh, accH[mf], 0, 0, 0);
            accL[mf] = __builtin_amdgcn_mfma_f32_16x16x32_f16(XL.v, wh, accL[mf], 0, 0, 0);
            accL[mf] = __builtin_amdgcn_mfma_f32_16x16x32_f16(XH.v, wl, accL[mf], 0, 0, 0);
        }
    }

    // layer-1 epilogue: lane holds h1[edge = lg*4+reg][feat = mf*16+lr].
    // bias+relu+split -> packed Y in wave-private LDS rows (no barrier).
    #pragma unroll
    for (int mf = 0; mf < 8; mf++) {
        const float bb1 = b1[mf * 16 + lr];
        #pragma unroll
        for (int reg = 0; reg < 4; reg++) {
            float v = accH[mf][reg] + accL[mf][reg] * (1.f / 2048.f) + bb1;
            v = fmaxf(v, 0.f);
            const f16 h = (f16)v;
            const f16 lo = (f16)((v - (float)h) * 2048.f);
            Yp[(w * 16 + lg * 4 + reg) * 132 + mf * 16 + lr] = pk2(h, lo);
        }
        accH[mf] = zero4; accL[mf] = zero4;
    }

    // ---------------- layer 2 (no barriers; Y read is wave-private) -------
    for (int kc = 0; kc < 4; ++kc) {
        union { uint32_t u[8]; } Q;
        const uint32_t* yrow = Yp + (w * 16 + lr) * 132 + kc * 32 + lg * 8;
        *(uint4*)&Q.u[0] = *(const uint4*)(yrow);
        *(uint4*)&Q.u[4] = *(const uint4*)(yrow + 4);
        union { f16 h[8]; f16x8 v; } XH, XL;
        #pragma unroll
        for (int j = 0; j < 8; j++) {
            union { uint32_t u; f16 h[2]; } c; c.u = Q.u[j];
            XH.h[j] = c.h[0];
            XL.h[j] = c.h[1];
        }
        #pragma unroll
        for (int mf = 0; mf < 8; mf++) {
            const size_t ro = (size_t)(mf * 16 + lr) * 128 + kc * 32 + lg * 8;
            const f16x8 wh = *(const f16x8*)(W2h + ro);
            const f16x8 wl = *(const f16x8*)(W2l + ro);
            accH[mf] = __builtin_amdgcn_mfma_f32_16x16x32_f16(XH.v, wh, accH[mf], 0, 0, 0);
            accL[mf] = __builtin_amdgcn_mfma_f32_16x16x32_f16(XL.v, wh, accL[mf], 0, 0, 0);
            accL[mf] = __builtin_amdgcn_mfma_f32_16x16x32_f16(XH.v, wl, accL[mf], 0, 0, 0);
        }
    }

    // layer-2 epilogue (round-1 verified pattern): bias+relu+LN+apply+store.
    float vv[8][4];
    float s1[4] = {0, 0, 0, 0}, s2[4] = {0, 0, 0, 0};
    #pragma unroll
    for (int mf = 0; mf < 8; mf++) {
        const float bb2 = b2[mf * 16 + lr];
        #pragma unroll
        for (int reg = 0; reg < 4; reg++) {
            float v = accH[mf][reg] + accL[mf][reg] * (1.f / 2048.f) + bb2;
            v = fmaxf(v, 0.f);
            vv[mf][reg] = v;
            s1[reg] += v; s2[reg] += v * v;
        }
    }
    #pragma unroll
    for (int m = 1; m < 16; m <<= 1) {
        #pragma unroll
        for (int reg = 0; reg < 4; reg++) {
            s1[reg] += __shfl_xor(s1[reg], m);
            s2[reg] += __shfl_xor(s2[reg], m);
        }
    }
    float gg[8], b8[8];
    #pragma unroll
    for (int mf = 0; mf < 8; mf++) {
        gg[mf] = gam[mf * 16 + lr];
        b8[mf] = bet[mf * 16 + lr];
    }

    #pragma unroll
    for (int reg = 0; reg < 4; reg++) {
        const float mu = s1[reg] * (1.f / 128.f);
        const float rs = rsqrtf(fmaxf(s2[reg] * (1.f / 128.f) - mu * mu, 0.f) + 1e-5f);
        const int row = w * 16 + lg * 4 + reg;
        const int idx = base + row;
        if (idx < nrows) {
            if constexpr (MODE == 0) {
                const int rc = receivers[idx];
                #pragma unroll
                for (int mf = 0; mf < 8; mf++) {
                    const float o = gg[mf] * (vv[mf][reg] - mu) * rs + b8[mf];
                    atomicAdd(&aggr[(size_t)rc * 128 + mf * 16 + lr], o); // segsum
                    io[(size_t)idx * 128 + mf * 16 + lr] += o;            // el res
                }
            } else if constexpr (MODE == 1) {
                #pragma unroll
                for (int mf = 0; mf < 8; mf++) {
                    const float o = gg[mf] * (vv[mf][reg] - mu) * rs + b8[mf];
                    io[(size_t)idx * 128 + mf * 16 + lr] += o;            // nl res
                }
            } else {
                #pragma unroll
                for (int mf = 0; mf < 8; mf++) {
                    const float o = gg[mf] * (vv[mf][reg] - mu) * rs + b8[mf];
                    io[(size_t)idx * 128 + mf * 16 + lr] = o;             // el enc
                }
            }
        }
    }
}

// Decoder -> FLOAT32 output, layout [TW, N, TD].
__global__ __launch_bounds__(128) void decode_k(
    const float* __restrict__ nl,
    const float* __restrict__ W1, const float* __restrict__ b1,
    const float* __restrict__ W2, const float* __restrict__ b2,
    float* __restrict__ out)
{
    constexpr int NPB = 16;
    __shared__ __align__(16) float xs[NPB * LNUM];
    __shared__ float hh[NPB * 8];
    const int t = threadIdx.x;
    const int base = blockIdx.x * NPB;
    for (int r = 0; r < NPB; r++) xs[r * LNUM + t] = nl[(base + r) * LNUM + t];
    __syncthreads();
    {
        const int node = t >> 3, j = t & 7;
        float a = b1[j];
        for (int k = 0; k < LNUM; k++) a = fmaf(xs[node * LNUM + k], W1[k * 8 + j], a);
        hh[node * 8 + j] = a / (1.f + expf(-a));
    }
    __syncthreads();
    for (int idx = t; idx < NPB * 10; idx += 128) {
        const int node = idx / 10, c = idx % 10;
        float a = b2[c];
        #pragma unroll
        for (int j = 0; j < 8; j++) a = fmaf(hh[node * 8 + j], W2[j * 10 + c], a);
        const int tt = c >> 1, d = c & 1;
        out[(size_t)tt * (NNODES * 2) + (size_t)(base + node) * 2 + d] =
            a * (float)(tt + 1);
    }
}

__global__ __launch_bounds__(256) void zero_k(float* __restrict__ p, int n)
{
    const int i = blockIdx.x * 256 + threadIdx.x;
    if (i < n) p[i] = 0.f;
}

// ---------------------------------------------------------------------------
extern "C" void kernel_launch(void* const* d_in, const int* in_sizes, int n_in,
                              void* d_out, int out_size, void* d_ws, size_t ws_size,
                              hipStream_t stream) {
    const float* F[34];
    for (int i = 0; i < 34; i++) F[i] = (const float*)d_in[i];
    const int* senders   = (const int*)d_in[4];
    const int* receivers = (const int*)d_in[5];

    const size_t nN = (size_t)NNODES * LNUM;
    const size_t nE = (size_t)NEDGES * LNUM;
    float* nl   = (float*)d_ws;
    float* el   = nl + nN;
    float* aggr = el + nE;
    f16* wb = (f16*)(aggr + nN);
    f16 *eW1h = wb,          *eW1l = eW1h + PE1;
    f16 *eW2h = eW1l + PE1,  *eW2l = eW2h + PE2;
    f16 *nW1h = eW2l + PE2,  *nW1l = nW1h + PN1;
    f16 *nW2h = nW1l + PN1,  *nW2l = nW2h + PN2;
    f16 *qW1h = nW2l + PN2,  *qW1l = qW1h + PQ1;
    f16 *qW2h = qW1l + PQ1,  *qW2l = qW2h + PQ2;

    prep_w_all_k<<<(PTOT + 255) / 256, 256, 0, stream>>>(
        F[18], F[20], F[24], F[26], F[12], F[14], wb);

    encode_nodes_k<<<NNODES / 4, 128, 0, stream>>>(
        F[2], F[3], F[1], F[6], F[7], F[8], F[9], F[10], F[11], nl);

    const int egrid = (NEDGES + 63) / 64;   // 2344
    const int ngrid = (NNODES + 63) / 64;   // 469

    // edge encoder (MFMA, computed features)
    mfma_mlp_k<2, 1, 32><<<egrid, 256, 0, stream>>>(
        F[0], F[2], el, nullptr, senders, receivers,
        qW1h, qW1l, F[13], qW2h, qW2l, F[15], F[16], F[17], NEDGES);

    for (int s = 0; s < NSTEPS; s++) {
        zero_k<<<(NNODES * LNUM + 255) / 256, 256, 0, stream>>>(aggr, NNODES * LNUM);
        mfma_mlp_k<0, 12, 384><<<egrid, 256, 0, stream>>>(
            nl, el, el, aggr, senders, receivers,
            eW1h + (size_t)s * 384 * 128, eW1l + (size_t)s * 384 * 128, F[19] + s * LNUM,
            eW2h + (size_t)s * 128 * 128, eW2l + (size_t)s * 128 * 128, F[21] + s * LNUM,
            F[22] + s * LNUM, F[23] + s * LNUM, NEDGES);
        mfma_mlp_k<1, 8, 256><<<ngrid, 256, 0, stream>>>(
            nl, aggr, nl, nullptr, nullptr, nullptr,
            nW1h + (size_t)s * 256 * 128, nW1l + (size_t)s * 256 * 128, F[25] + s * LNUM,
            nW2h + (size_t)s * 128 * 128, nW2l + (size_t)s * 128 * 128, F[27] + s * LNUM,
            F[28] + s * LNUM, F[29] + s * LNUM, NNODES);
    }

    decode_k<<<NNODES / 16, 128, 0, stream>>>(
        nl, F[30], F[31], F[32], F[33], (float*)d_out);
}

// Round 5
// 1192.671 us; speedup vs baseline: 2.0576x; 2.0576x over previous
//
#include <hip/hip_runtime.h>
#include <hip/hip_bf16.h>

#define LNUM 128
#define NNODES 30000
#define NEDGES 150000
#define NSTEPS 5

// NOTE (r17 discovery): d_out is FLOAT32 (reference is pure jnp.float32).
// Split-f16 numerics: x = hi + lo/2048 -> 3 MFMAs per frag pair, ~f32 accuracy.
// r4 post-mortem: per-wave direct weight loads = 4x redundant L1 traffic,
// latency-bound at 21% occupancy (390us vs r1's 201us staged version).
// r5: r2's VERIFIED glds16+XOR-swizzle cooperative weight staging (16KB,
// 2-barrier K-step, m97 pattern) + r4's VERIFIED reg-gather / non-swapped
// MFMA / Yp transpose / full-line epilogue + 1-deep data-gather prefetch.

typedef _Float16 f16;
typedef __attribute__((ext_vector_type(8))) _Float16 f16x8;
typedef __attribute__((ext_vector_type(4))) float f32x4;

__device__ __forceinline__ void glds16(const void* g, void* l) {
    __builtin_amdgcn_global_load_lds(
        (const __attribute__((address_space(1))) void*)g,
        (__attribute__((address_space(3))) void*)l, 16, 0, 0);
}

__device__ __forceinline__ uint32_t pk2(f16 a, f16 b) {
    union { f16 h[2]; uint32_t u; } x; x.h[0] = a; x.h[1] = b; return x.u;
}

// ---------------------------------------------------------------------------
// Legacy VALU MLP core: still used by the (small) encode_nodes kernel.
// ---------------------------------------------------------------------------
template<int ROWS, int K, int KP>
__device__ __forceinline__ void mlp_apply(
    const float* __restrict__ xs, float* __restrict__ hv,
    float* __restrict__ mu_s, float* __restrict__ rs_s,
    const float* __restrict__ W1, const float* __restrict__ b1,
    const float* __restrict__ W2, const float* __restrict__ b2,
    const float* __restrict__ g,  const float* __restrict__ be,
    float out[ROWS])
{
    const int t = threadIdx.x;
    float acc[ROWS];
    {
        const float bb = b1[t];
        #pragma unroll
        for (int r = 0; r < ROWS; r++) acc[r] = bb;
    }
    int k = 0;
    for (; k + 4 <= K; k += 4) {
        const float w0 = W1[(k + 0) * LNUM + t];
        const float w1 = W1[(k + 1) * LNUM + t];
        const float w2 = W1[(k + 2) * LNUM + t];
        const float w3 = W1[(k + 3) * LNUM + t];
        #pragma unroll
        for (int r = 0; r < ROWS; r++) {
            const float4 x = *(const float4*)(xs + r * KP + k);
            acc[r] = fmaf(x.x, w0, acc[r]);
            acc[r] = fmaf(x.y, w1, acc[r]);
            acc[r] = fmaf(x.z, w2, acc[r]);
            acc[r] = fmaf(x.w, w3, acc[r]);
        }
    }
    for (; k < K; ++k) {
        const float w = W1[k * LNUM + t];
        #pragma unroll
        for (int r = 0; r < ROWS; r++) acc[r] = fmaf(xs[r * KP + k], w, acc[r]);
    }
    #pragma unroll
    for (int r = 0; r < ROWS; r++) hv[r * LNUM + t] = fmaxf(acc[r], 0.f);
    __syncthreads();
    {
        const float bb = b2[t];
        #pragma unroll
        for (int r = 0; r < ROWS; r++) acc[r] = bb;
    }
    for (int k2 = 0; k2 < LNUM; k2 += 4) {
        const float w0 = W2[(k2 + 0) * LNUM + t];
        const float w1 = W2[(k2 + 1) * LNUM + t];
        const float w2 = W2[(k2 + 2) * LNUM + t];
        const float w3 = W2[(k2 + 3) * LNUM + t];
        #pragma unroll
        for (int r = 0; r < ROWS; r++) {
            const float4 x = *(const float4*)(hv + r * LNUM + k2);
            acc[r] = fmaf(x.x, w0, acc[r]);
            acc[r] = fmaf(x.y, w1, acc[r]);
            acc[r] = fmaf(x.z, w2, acc[r]);
            acc[r] = fmaf(x.w, w3, acc[r]);
        }
    }
    __syncthreads();
    #pragma unroll
    for (int r = 0; r < ROWS; r++) hv[r * LNUM + t] = fmaxf(acc[r], 0.f);
    __syncthreads();
    if (t < ROWS) {
        float s = 0.f, s2 = 0.f;
        for (int kk = 0; kk < LNUM; kk++) {
            const float v = hv[t * LNUM + kk];
            s += v; s2 += v * v;
        }
        const float m = s * (1.0f / LNUM);
        mu_s[t] = m;
        rs_s[t] = rsqrtf(fmaxf(s2 * (1.0f / LNUM) - m * m, 0.f) + 1e-5f);
    }
    __syncthreads();
    const float gg = g[t], bbe = be[t];
    #pragma unroll
    for (int r = 0; r < ROWS; r++)
        out[r] = fmaf(gg * (hv[r * LNUM + t] - mu_s[r]), rs_s[r], bbe);
}

__global__ __launch_bounds__(128) void encode_nodes_k(
    const float* __restrict__ u, const float* __restrict__ load_,
    const float* __restrict__ ntype,
    const float* __restrict__ W1, const float* __restrict__ b1,
    const float* __restrict__ W2, const float* __restrict__ b2,
    const float* __restrict__ g,  const float* __restrict__ be,
    float* __restrict__ nl)
{
    constexpr int ROWS = 4, K = 12, KP = 12;
    __shared__ __align__(16) float xs[ROWS * KP];
    __shared__ __align__(16) float hv[ROWS * LNUM];
    __shared__ float mu_s[ROWS], rs_s[ROWS];
    const int t = threadIdx.x;
    const int base = blockIdx.x * ROWS;
    if (t < ROWS * K) {
        const int r = t / K, k = t % K;
        const int n = base + r;
        float v;
        if (k < 2)      v = u[n * 2 + k];
        else if (k < 3) v = load_[n];
        else            v = ntype[n * 9 + (k - 3)];
        xs[r * KP + k] = v;
    }
    __syncthreads();
    float out[ROWS];
    mlp_apply<ROWS, K, KP>(xs, hv, mu_s, rs_s, W1, b1, W2, b2, g, be, out);
    #pragma unroll
    for (int r = 0; r < ROWS; r++) nl[(base + r) * LNUM + t] = out[r];
}

// ---------------------------------------------------------------------------
// Weight prep: f32 [S][K][128] -> f16 hi/lo tables transposed to [S][128][K].
// ---------------------------------------------------------------------------
#define PE1 245760   // 5*384*128 (edge W1)
#define PE2 81920    // 5*128*128 (edge W2)
#define PN1 163840   // 5*256*128 (node W1)
#define PN2 81920    // 5*128*128 (node W2)
#define PQ1 4096     // 128*32    (enc-edge W1, k-padded)
#define PQ2 16384    // 128*128   (enc-edge W2)
#define PTOT (PE1+PE2+PN1+PN2+PQ1+PQ2)

__global__ __launch_bounds__(256) void prep_w_all_k(
    const float* __restrict__ eW1, const float* __restrict__ eW2,
    const float* __restrict__ nW1, const float* __restrict__ nW2,
    const float* __restrict__ qW1, const float* __restrict__ qW2,
    f16* __restrict__ out)
{
    int j = blockIdx.x * 256 + threadIdx.x;
    if (j >= PTOT) return;
    const float* W; int K, kreal; f16 *hi, *lo; f16* p = out;
    if (j < PE1) { W = eW1; K = 384; kreal = 384; hi = p; lo = p + PE1; }
    else { p += 2 * PE1; j -= PE1;
    if (j < PE2) { W = eW2; K = 128; kreal = 128; hi = p; lo = p + PE2; }
    else { p += 2 * PE2; j -= PE2;
    if (j < PN1) { W = nW1; K = 256; kreal = 256; hi = p; lo = p + PN1; }
    else { p += 2 * PN1; j -= PN1;
    if (j < PN2) { W = nW2; K = 128; kreal = 128; hi = p; lo = p + PN2; }
    else { p += 2 * PN2; j -= PN2;
    if (j < PQ1) { W = qW1; K = 32;  kreal = 5;   hi = p; lo = p + PQ1; }
    else { p += 2 * PQ1; j -= PQ1;
         { W = qW2; K = 128; kreal = 128; hi = p; lo = p + PQ2; } } } } } }
    const int k = j % K;
    const int rem = j / K;
    const int n = rem & 127;
    const int s = rem >> 7;
    const float v = (k < kreal) ? W[((size_t)s * kreal + k) * 128 + n] : 0.f;
    const f16 h = (f16)v;
    hi[j] = h;
    lo[j] = (f16)((v - (float)h) * 2048.f);
}

// ---------------------------------------------------------------------------
// MFMA MLP, cooperative weight staging. 256 threads = 4 waves, 64 rows/block.
// Weights: ONE 32-wide K chunk (hi+lo, 16KB) staged per iter via
// global_load_lds with the r2-verified XOR swizzle (o^=((o>>7)&3)<<4);
// 2 barriers per chunk (m97 pattern). Read back as the exact fragment
// W[mf*16+lr][kc*32+lg*8..+8] (bit-identical to r4's direct loads).
// Data: gathered per-lane to regs, prefetched 1 chunk ahead (issued right
// after the stage-drain barrier, hides under 24 MFMA + 16 ds_read).
// Layer1->2 transpose via wave-private packed Yp (no extra barriers).
// D layout (r1/r4-verified): edge = w*16+lg*4+reg, feature = mf*16+lr
// -> epilogue writes/atomics are 16-consecutive-col (full 64B lines).
// MODE: 0 = edge block, 1 = node block, 2 = edge encoder.
// ---------------------------------------------------------------------------
template<int MODE, int NCH1, int K1S>
__global__ __launch_bounds__(256) void mfma_mlp_k(
    const float* __restrict__ in0, const float* __restrict__ in1,
    float* __restrict__ io, float* __restrict__ aggr,
    const int* __restrict__ senders, const int* __restrict__ receivers,
    const f16* __restrict__ W1h, const f16* __restrict__ W1l, const float* __restrict__ b1,
    const f16* __restrict__ W2h, const f16* __restrict__ W2l, const float* __restrict__ b2,
    const float* __restrict__ gam, const float* __restrict__ bet,
    int nrows)
{
    __shared__ __align__(16) f16 WH[4096];            // [128][32] swizzled, 8KB
    __shared__ __align__(16) f16 WL[4096];            // 8KB
    __shared__ __align__(16) uint32_t Yp[64 * 132];   // packed hi|lo, 33.8KB

    const int t  = threadIdx.x;
    const int w  = t >> 6;
    const int l  = t & 63;
    const int lr = l & 15;
    const int lg = l >> 4;
    const int swz = lg ^ ((lr >> 1) & 3);
    const int base = blockIdx.x * 64;

    const int eg  = base + w * 16 + lr;    // this lane's gather row (A-row)
    const int egc = min(eg, nrows - 1);

    int sv = 0, rv = 0;
    if constexpr (MODE != 1) { sv = senders[egc]; rv = receivers[egc]; }

    float feat[8];
    if constexpr (MODE == 2) {
        const float ax = in0[sv * 2], ay = in0[sv * 2 + 1];
        const float bx = in0[rv * 2], by = in0[rv * 2 + 1];
        const float rx = ax - bx, ry = ay - by;
        feat[0] = rx; feat[1] = ry; feat[2] = sqrtf(rx * rx + ry * ry);
        feat[3] = in1[sv * 2] - in1[rv * 2];
        feat[4] = in1[sv * 2 + 1] - in1[rv * 2 + 1];
        feat[5] = 0.f; feat[6] = 0.f; feat[7] = 0.f;
    }

    // r2-verified cooperative stage of one 32-wide K chunk (hi+lo).
    auto stage = [&](const f16* __restrict__ Wh, const f16* __restrict__ Wl,
                     const int kst, const int kc) {
        #pragma unroll
        for (int i = 0; i < 2; i++) {
            const int c = 2 * w + i;
            const int ophys = c * 1024 + l * 16;
            const int olog  = ophys ^ (((ophys >> 7) & 3) << 4);
            const int row   = olog >> 6;
            const int slot  = (olog >> 4) & 3;
            glds16(Wh + (size_t)row * kst + kc * 32 + slot * 8, (char*)WH + c * 1024);
            glds16(Wl + (size_t)row * kst + kc * 32 + slot * 8, (char*)WL + c * 1024);
        }
    };

    // r4-verified per-lane data gather (raw f32, 8 elems).
    auto gather = [&](int kc, float xv[8]) {
        if constexpr (MODE == 2) {
            #pragma unroll
            for (int j = 0; j < 8; j++) xv[j] = (lg == 0) ? feat[j] : 0.f;
        } else {
            const float* src;
            if constexpr (MODE == 0) {
                if (kc < 4)      src = in0 + (size_t)sv  * 128 + kc * 32 + lg * 8;
                else if (kc < 8) src = in0 + (size_t)rv  * 128 + (kc - 4) * 32 + lg * 8;
                else             src = in1 + (size_t)egc * 128 + (kc - 8) * 32 + lg * 8;
            } else {
                if (kc < 4) src = in0 + (size_t)egc * 128 + kc * 32 + lg * 8;
                else        src = in1 + (size_t)egc * 128 + (kc - 4) * 32 + lg * 8;
            }
            const float4 x0 = *(const float4*)src;
            const float4 x1 = *(const float4*)(src + 4);
            xv[0] = x0.x; xv[1] = x0.y; xv[2] = x0.z; xv[3] = x0.w;
            xv[4] = x1.x; xv[5] = x1.y; xv[6] = x1.z; xv[7] = x1.w;
        }
    };

    const f32x4 zero4 = {0.f, 0.f, 0.f, 0.f};
    f32x4 accH[8], accL[8];
    #pragma unroll
    for (int mf = 0; mf < 8; mf++) { accH[mf] = zero4; accL[mf] = zero4; }

    float xnext[8];
    gather(0, xnext);

    // ---------------- layer 1 ----------------
    for (int kc = 0; kc < NCH1; ++kc) {
        __syncthreads();                      // prior readers done (drains xnext)
        stage(W1h, W1l, K1S, kc);
        __syncthreads();                      // weights staged
        union { f16 h[8]; f16x8 v; } XH, XL;
        #pragma unroll
        for (int j = 0; j < 8; j++) {
            const f16 h = (f16)xnext[j];
            XH.h[j] = h;
            XL.h[j] = (f16)((xnext[j] - (float)h) * 2048.f);
        }
        if (kc + 1 < NCH1) gather(kc + 1, xnext);   // prefetch next chunk
        #pragma unroll
        for (int mf = 0; mf < 8; mf++) {
            const int off = (mf * 16 + lr) * 64 + (swz << 4);
            const f16x8 wh = *(const f16x8*)((const char*)WH + off);
            const f16x8 wl = *(const f16x8*)((const char*)WL + off);
            accH[mf] = __builtin_amdgcn_mfma_f32_16x16x32_f16(XH.v, wh, accH[mf], 0, 0, 0);
            accL[mf] = __builtin_amdgcn_mfma_f32_16x16x32_f16(XL.v, wh, accL[mf], 0, 0, 0);
            accL[mf] = __builtin_amdgcn_mfma_f32_16x16x32_f16(XH.v, wl, accL[mf], 0, 0, 0);
        }
    }

    // layer-1 epilogue: lane holds h1[edge = lg*4+reg][feat = mf*16+lr].
    // bias+relu+split -> packed Y in wave-private LDS rows (no barrier).
    #pragma unroll
    for (int mf = 0; mf < 8; mf++) {
        const float bb1 = b1[mf * 16 + lr];
        #pragma unroll
        for (int reg = 0; reg < 4; reg++) {
            float v = accH[mf][reg] + accL[mf][reg] * (1.f / 2048.f) + bb1;
            v = fmaxf(v, 0.f);
            const f16 h = (f16)v;
            const f16 lo = (f16)((v - (float)h) * 2048.f);
            Yp[(w * 16 + lg * 4 + reg) * 132 + mf * 16 + lr] = pk2(h, lo);
        }
        accH[mf] = zero4; accL[mf] = zero4;
    }

    // ---------------- layer 2 ----------------
    for (int kc = 0; kc < 4; ++kc) {
        __syncthreads();
        stage(W2h, W2l, 128, kc);
        __syncthreads();
        union { uint32_t u[8]; } Q;
        const uint32_t* yrow = Yp + (w * 16 + lr) * 132 + kc * 32 + lg * 8;
        *(uint4*)&Q.u[0] = *(const uint4*)(yrow);
        *(uint4*)&Q.u[4] = *(const uint4*)(yrow + 4);
        union { f16 h[8]; f16x8 v; } XH, XL;
        #pragma unroll
        for (int j = 0; j < 8; j++) {
            union { uint32_t u; f16 h[2]; } c; c.u = Q.u[j];
            XH.h[j] = c.h[0];
            XL.h[j] = c.h[1];
        }
        #pragma unroll
        for (int mf = 0; mf < 8; mf++) {
            const int off = (mf * 16 + lr) * 64 + (swz << 4);
            const f16x8 wh = *(const f16x8*)((const char*)WH + off);
            const f16x8 wl = *(const f16x8*)((const char*)WL + off);
            accH[mf] = __builtin_amdgcn_mfma_f32_16x16x32_f16(XH.v, wh, accH[mf], 0, 0, 0);
            accL[mf] = __builtin_amdgcn_mfma_f32_16x16x32_f16(XL.v, wh, accL[mf], 0, 0, 0);
            accL[mf] = __builtin_amdgcn_mfma_f32_16x16x32_f16(XH.v, wl, accL[mf], 0, 0, 0);
        }
    }

    // layer-2 epilogue (r4-verified): bias+relu+LN+apply+store.
    float vv[8][4];
    float s1[4] = {0, 0, 0, 0}, s2[4] = {0, 0, 0, 0};
    #pragma unroll
    for (int mf = 0; mf < 8; mf++) {
        const float bb2 = b2[mf * 16 + lr];
        #pragma unroll
        for (int reg = 0; reg < 4; reg++) {
            float v = accH[mf][reg] + accL[mf][reg] * (1.f / 2048.f) + bb2;
            v = fmaxf(v, 0.f);
            vv[mf][reg] = v;
            s1[reg] += v; s2[reg] += v * v;
        }
    }
    #pragma unroll
    for (int m = 1; m < 16; m <<= 1) {
        #pragma unroll
        for (int reg = 0; reg < 4; reg++) {
            s1[reg] += __shfl_xor(s1[reg], m);
            s2[reg] += __shfl_xor(s2[reg], m);
        }
    }
    float gg[8], b8[8];
    #pragma unroll
    for (int mf = 0; mf < 8; mf++) {
        gg[mf] = gam[mf * 16 + lr];
        b8[mf] = bet[mf * 16 + lr];
    }

    #pragma unroll
    for (int reg = 0; reg < 4; reg++) {
        const float mu = s1[reg] * (1.f / 128.f);
        const float rs = rsqrtf(fmaxf(s2[reg] * (1.f / 128.f) - mu * mu, 0.f) + 1e-5f);
        const int row = w * 16 + lg * 4 + reg;
        const int idx = base + row;
        if (idx < nrows) {
            if constexpr (MODE == 0) {
                const int rc = receivers[idx];
                #pragma unroll
                for (int mf = 0; mf < 8; mf++) {
                    const float o = gg[mf] * (vv[mf][reg] - mu) * rs + b8[mf];
                    atomicAdd(&aggr[(size_t)rc * 128 + mf * 16 + lr], o); // segsum
                    io[(size_t)idx * 128 + mf * 16 + lr] += o;            // el res
                }
            } else if constexpr (MODE == 1) {
                #pragma unroll
                for (int mf = 0; mf < 8; mf++) {
                    const float o = gg[mf] * (vv[mf][reg] - mu) * rs + b8[mf];
                    io[(size_t)idx * 128 + mf * 16 + lr] += o;            // nl res
                }
            } else {
                #pragma unroll
                for (int mf = 0; mf < 8; mf++) {
                    const float o = gg[mf] * (vv[mf][reg] - mu) * rs + b8[mf];
                    io[(size_t)idx * 128 + mf * 16 + lr] = o;             // el enc
                }
            }
        }
    }
}

// Decoder -> FLOAT32 output, layout [TW, N, TD].
__global__ __launch_bounds__(128) void decode_k(
    const float* __restrict__ nl,
    const float* __restrict__ W1, const float* __restrict__ b1,
    const float* __restrict__ W2, const float* __restrict__ b2,
    float* __restrict__ out)
{
    constexpr int NPB = 16;
    __shared__ __align__(16) float xs[NPB * LNUM];
    __shared__ float hh[NPB * 8];
    const int t = threadIdx.x;
    const int base = blockIdx.x * NPB;
    for (int r = 0; r < NPB; r++) xs[r * LNUM + t] = nl[(base + r) * LNUM + t];
    __syncthreads();
    {
        const int node = t >> 3, j = t & 7;
        float a = b1[j];
        for (int k = 0; k < LNUM; k++) a = fmaf(xs[node * LNUM + k], W1[k * 8 + j], a);
        hh[node * 8 + j] = a / (1.f + expf(-a));
    }
    __syncthreads();
    for (int idx = t; idx < NPB * 10; idx += 128) {
        const int node = idx / 10, c = idx % 10;
        float a = b2[c];
        #pragma unroll
        for (int j = 0; j < 8; j++) a = fmaf(hh[node * 8 + j], W2[j * 10 + c], a);
        const int tt = c >> 1, d = c & 1;
        out[(size_t)tt * (NNODES * 2) + (size_t)(base + node) * 2 + d] =
            a * (float)(tt + 1);
    }
}

__global__ __launch_bounds__(256) void zero_k(float* __restrict__ p, int n)
{
    const int i = blockIdx.x * 256 + threadIdx.x;
    if (i < n) p[i] = 0.f;
}

// ---------------------------------------------------------------------------
extern "C" void kernel_launch(void* const* d_in, const int* in_sizes, int n_in,
                              void* d_out, int out_size, void* d_ws, size_t ws_size,
                              hipStream_t stream) {
    const float* F[34];
    for (int i = 0; i < 34; i++) F[i] = (const float*)d_in[i];
    const int* senders   = (const int*)d_in[4];
    const int* receivers = (const int*)d_in[5];

    const size_t nN = (size_t)NNODES * LNUM;
    const size_t nE = (size_t)NEDGES * LNUM;
    float* nl   = (float*)d_ws;
    float* el   = nl + nN;
    float* aggr = el + nE;
    f16* wb = (f16*)(aggr + nN);
    f16 *eW1h = wb,          *eW1l = eW1h + PE1;
    f16 *eW2h = eW1l + PE1,  *eW2l = eW2h + PE2;
    f16 *nW1h = eW2l + PE2,  *nW1l = nW1h + PN1;
    f16 *nW2h = nW1l + PN1,  *nW2l = nW2h + PN2;
    f16 *qW1h = nW2l + PN2,  *qW1l = qW1h + PQ1;
    f16 *qW2h = qW1l + PQ1,  *qW2l = qW2h + PQ2;

    prep_w_all_k<<<(PTOT + 255) / 256, 256, 0, stream>>>(
        F[18], F[20], F[24], F[26], F[12], F[14], wb);

    encode_nodes_k<<<NNODES / 4, 128, 0, stream>>>(
        F[2], F[3], F[1], F[6], F[7], F[8], F[9], F[10], F[11], nl);

    const int egrid = (NEDGES + 63) / 64;   // 2344
    const int ngrid = (NNODES + 63) / 64;   // 469

    // edge encoder (MFMA, computed features)
    mfma_mlp_k<2, 1, 32><<<egrid, 256, 0, stream>>>(
        F[0], F[2], el, nullptr, senders, receivers,
        qW1h, qW1l, F[13], qW2h, qW2l, F[15], F[16], F[17], NEDGES);

    for (int s = 0; s < NSTEPS; s++) {
        zero_k<<<(NNODES * LNUM + 255) / 256, 256, 0, stream>>>(aggr, NNODES * LNUM);
        mfma_mlp_k<0, 12, 384><<<egrid, 256, 0, stream>>>(
            nl, el, el, aggr, senders, receivers,
            eW1h + (size_t)s * 384 * 128, eW1l + (size_t)s * 384 * 128, F[19] + s * LNUM,
            eW2h + (size_t)s * 128 * 128, eW2l + (size_t)s * 128 * 128, F[21] + s * LNUM,
            F[22] + s * LNUM, F[23] + s * LNUM, NEDGES);
        mfma_mlp_k<1, 8, 256><<<ngrid, 256, 0, stream>>>(
            nl, aggr, nl, nullptr, nullptr, nullptr,
            nW1h + (size_t)s * 256 * 128, nW1l + (size_t)s * 256 * 128, F[25] + s * LNUM,
            nW2h + (size_t)s * 128 * 128, nW2l + (size_t)s * 128 * 128, F[27] + s * LNUM,
            F[28] + s * LNUM, F[29] + s * LNUM, NNODES);
    }

    decode_k<<<NNODES / 16, 128, 0, stream>>>(
        nl, F[30], F[31], F[32], F[33], (float*)d_out);
}

// Round 6
// 1189.476 us; speedup vs baseline: 2.0632x; 1.0027x over previous
//
#include <hip/hip_runtime.h>
#include <hip/hip_bf16.h>

#define LNUM 128
#define NNODES 30000
#define NEDGES 150000
#define NSTEPS 5

// NOTE (r17 discovery): d_out is FLOAT32 (reference is pure jnp.float32).
// Split-f16 numerics: x = hi + lo/2048 -> 3 MFMAs per frag pair, ~f32 accuracy.
// r5 post-mortem: weight stage issued immediately before the draining barrier
// -> full L2 latency exposed 16x/block (MfmaUtil 13%). r6: double-buffered
// weight LDS (T3 minimum-2-phase): ONE barrier per chunk, stage chunk k+1
// issued before chunk k's MFMAs. Arithmetic bit-identical to r5.

typedef _Float16 f16;
typedef __attribute__((ext_vector_type(8))) _Float16 f16x8;
typedef __attribute__((ext_vector_type(4))) float f32x4;

__device__ __forceinline__ void glds16(const void* g, void* l) {
    __builtin_amdgcn_global_load_lds(
        (const __attribute__((address_space(1))) void*)g,
        (__attribute__((address_space(3))) void*)l, 16, 0, 0);
}

__device__ __forceinline__ uint32_t pk2(f16 a, f16 b) {
    union { f16 h[2]; uint32_t u; } x; x.h[0] = a; x.h[1] = b; return x.u;
}

// ---------------------------------------------------------------------------
// Legacy VALU MLP core: still used by the (small) encode_nodes kernel.
// ---------------------------------------------------------------------------
template<int ROWS, int K, int KP>
__device__ __forceinline__ void mlp_apply(
    const float* __restrict__ xs, float* __restrict__ hv,
    float* __restrict__ mu_s, float* __restrict__ rs_s,
    const float* __restrict__ W1, const float* __restrict__ b1,
    const float* __restrict__ W2, const float* __restrict__ b2,
    const float* __restrict__ g,  const float* __restrict__ be,
    float out[ROWS])
{
    const int t = threadIdx.x;
    float acc[ROWS];
    {
        const float bb = b1[t];
        #pragma unroll
        for (int r = 0; r < ROWS; r++) acc[r] = bb;
    }
    int k = 0;
    for (; k + 4 <= K; k += 4) {
        const float w0 = W1[(k + 0) * LNUM + t];
        const float w1 = W1[(k + 1) * LNUM + t];
        const float w2 = W1[(k + 2) * LNUM + t];
        const float w3 = W1[(k + 3) * LNUM + t];
        #pragma unroll
        for (int r = 0; r < ROWS; r++) {
            const float4 x = *(const float4*)(xs + r * KP + k);
            acc[r] = fmaf(x.x, w0, acc[r]);
            acc[r] = fmaf(x.y, w1, acc[r]);
            acc[r] = fmaf(x.z, w2, acc[r]);
            acc[r] = fmaf(x.w, w3, acc[r]);
        }
    }
    for (; k < K; ++k) {
        const float w = W1[k * LNUM + t];
        #pragma unroll
        for (int r = 0; r < ROWS; r++) acc[r] = fmaf(xs[r * KP + k], w, acc[r]);
    }
    #pragma unroll
    for (int r = 0; r < ROWS; r++) hv[r * LNUM + t] = fmaxf(acc[r], 0.f);
    __syncthreads();
    {
        const float bb = b2[t];
        #pragma unroll
        for (int r = 0; r < ROWS; r++) acc[r] = bb;
    }
    for (int k2 = 0; k2 < LNUM; k2 += 4) {
        const float w0 = W2[(k2 + 0) * LNUM + t];
        const float w1 = W2[(k2 + 1) * LNUM + t];
        const float w2 = W2[(k2 + 2) * LNUM + t];
        const float w3 = W2[(k2 + 3) * LNUM + t];
        #pragma unroll
        for (int r = 0; r < ROWS; r++) {
            const float4 x = *(const float4*)(hv + r * LNUM + k2);
            acc[r] = fmaf(x.x, w0, acc[r]);
            acc[r] = fmaf(x.y, w1, acc[r]);
            acc[r] = fmaf(x.z, w2, acc[r]);
            acc[r] = fmaf(x.w, w3, acc[r]);
        }
    }
    __syncthreads();
    #pragma unroll
    for (int r = 0; r < ROWS; r++) hv[r * LNUM + t] = fmaxf(acc[r], 0.f);
    __syncthreads();
    if (t < ROWS) {
        float s = 0.f, s2 = 0.f;
        for (int kk = 0; kk < LNUM; kk++) {
            const float v = hv[t * LNUM + kk];
            s += v; s2 += v * v;
        }
        const float m = s * (1.0f / LNUM);
        mu_s[t] = m;
        rs_s[t] = rsqrtf(fmaxf(s2 * (1.0f / LNUM) - m * m, 0.f) + 1e-5f);
    }
    __syncthreads();
    const float gg = g[t], bbe = be[t];
    #pragma unroll
    for (int r = 0; r < ROWS; r++)
        out[r] = fmaf(gg * (hv[r * LNUM + t] - mu_s[r]), rs_s[r], bbe);
}

__global__ __launch_bounds__(128) void encode_nodes_k(
    const float* __restrict__ u, const float* __restrict__ load_,
    const float* __restrict__ ntype,
    const float* __restrict__ W1, const float* __restrict__ b1,
    const float* __restrict__ W2, const float* __restrict__ b2,
    const float* __restrict__ g,  const float* __restrict__ be,
    float* __restrict__ nl)
{
    constexpr int ROWS = 4, K = 12, KP = 12;
    __shared__ __align__(16) float xs[ROWS * KP];
    __shared__ __align__(16) float hv[ROWS * LNUM];
    __shared__ float mu_s[ROWS], rs_s[ROWS];
    const int t = threadIdx.x;
    const int base = blockIdx.x * ROWS;
    if (t < ROWS * K) {
        const int r = t / K, k = t % K;
        const int n = base + r;
        float v;
        if (k < 2)      v = u[n * 2 + k];
        else if (k < 3) v = load_[n];
        else            v = ntype[n * 9 + (k - 3)];
        xs[r * KP + k] = v;
    }
    __syncthreads();
    float out[ROWS];
    mlp_apply<ROWS, K, KP>(xs, hv, mu_s, rs_s, W1, b1, W2, b2, g, be, out);
    #pragma unroll
    for (int r = 0; r < ROWS; r++) nl[(base + r) * LNUM + t] = out[r];
}

// ---------------------------------------------------------------------------
// Weight prep: f32 [S][K][128] -> f16 hi/lo tables transposed to [S][128][K].
// ---------------------------------------------------------------------------
#define PE1 245760   // 5*384*128 (edge W1)
#define PE2 81920    // 5*128*128 (edge W2)
#define PN1 163840   // 5*256*128 (node W1)
#define PN2 81920    // 5*128*128 (node W2)
#define PQ1 4096     // 128*32    (enc-edge W1, k-padded)
#define PQ2 16384    // 128*128   (enc-edge W2)
#define PTOT (PE1+PE2+PN1+PN2+PQ1+PQ2)

__global__ __launch_bounds__(256) void prep_w_all_k(
    const float* __restrict__ eW1, const float* __restrict__ eW2,
    const float* __restrict__ nW1, const float* __restrict__ nW2,
    const float* __restrict__ qW1, const float* __restrict__ qW2,
    f16* __restrict__ out)
{
    int j = blockIdx.x * 256 + threadIdx.x;
    if (j >= PTOT) return;
    const float* W; int K, kreal; f16 *hi, *lo; f16* p = out;
    if (j < PE1) { W = eW1; K = 384; kreal = 384; hi = p; lo = p + PE1; }
    else { p += 2 * PE1; j -= PE1;
    if (j < PE2) { W = eW2; K = 128; kreal = 128; hi = p; lo = p + PE2; }
    else { p += 2 * PE2; j -= PE2;
    if (j < PN1) { W = nW1; K = 256; kreal = 256; hi = p; lo = p + PN1; }
    else { p += 2 * PN1; j -= PN1;
    if (j < PN2) { W = nW2; K = 128; kreal = 128; hi = p; lo = p + PN2; }
    else { p += 2 * PN2; j -= PN2;
    if (j < PQ1) { W = qW1; K = 32;  kreal = 5;   hi = p; lo = p + PQ1; }
    else { p += 2 * PQ1; j -= PQ1;
         { W = qW2; K = 128; kreal = 128; hi = p; lo = p + PQ2; } } } } } }
    const int k = j % K;
    const int rem = j / K;
    const int n = rem & 127;
    const int s = rem >> 7;
    const float v = (k < kreal) ? W[((size_t)s * kreal + k) * 128 + n] : 0.f;
    const f16 h = (f16)v;
    hi[j] = h;
    lo[j] = (f16)((v - (float)h) * 2048.f);
}

// ---------------------------------------------------------------------------
// MFMA MLP, DOUBLE-BUFFERED cooperative weight staging (T3 minimum-2-phase).
// 256 threads = 4 waves, 64 rows/block. Per chunk: ONE barrier, then issue
// glds for chunk k+1 into buf^1, then MFMAs from buf (stage latency spans
// the whole compute phase). Layer-2 chunk 0 prefetched during last layer-1
// iteration. Fragment contents bit-identical to r5 (swizzle is 8KB-buffer-
// relative; +8192 offset doesn't touch bits 7-8).
// Data: per-lane reg gather, prefetched 1 chunk ahead.
// Layer1->2 transpose via wave-private packed Yp (no extra barriers).
// D layout (r1/r4-verified): edge = w*16+lg*4+reg, feature = mf*16+lr
// -> epilogue writes/atomics are 16-consecutive-col (full 64B lines).
// MODE: 0 = edge block, 1 = node block, 2 = edge encoder.
// ---------------------------------------------------------------------------
template<int MODE, int NCH1, int K1S>
__global__ __launch_bounds__(256) void mfma_mlp_k(
    const float* __restrict__ in0, const float* __restrict__ in1,
    float* __restrict__ io, float* __restrict__ aggr,
    const int* __restrict__ senders, const int* __restrict__ receivers,
    const f16* __restrict__ W1h, const f16* __restrict__ W1l, const float* __restrict__ b1,
    const f16* __restrict__ W2h, const f16* __restrict__ W2l, const float* __restrict__ b2,
    const float* __restrict__ gam, const float* __restrict__ bet,
    int nrows)
{
    __shared__ __align__(16) f16 WH[2][4096];         // [buf][128][32] swz, 16KB
    __shared__ __align__(16) f16 WL[2][4096];         // 16KB
    __shared__ __align__(16) uint32_t Yp[64 * 132];   // packed hi|lo, 33.8KB

    const int t  = threadIdx.x;
    const int w  = t >> 6;
    const int l  = t & 63;
    const int lr = l & 15;
    const int lg = l >> 4;
    const int swz = lg ^ ((lr >> 1) & 3);
    const int base = blockIdx.x * 64;

    const int eg  = base + w * 16 + lr;    // this lane's gather row (A-row)
    const int egc = min(eg, nrows - 1);

    int sv = 0, rv = 0;
    if constexpr (MODE != 1) { sv = senders[egc]; rv = receivers[egc]; }

    float feat[8];
    if constexpr (MODE == 2) {
        const float ax = in0[sv * 2], ay = in0[sv * 2 + 1];
        const float bx = in0[rv * 2], by = in0[rv * 2 + 1];
        const float rx = ax - bx, ry = ay - by;
        feat[0] = rx; feat[1] = ry; feat[2] = sqrtf(rx * rx + ry * ry);
        feat[3] = in1[sv * 2] - in1[rv * 2];
        feat[4] = in1[sv * 2 + 1] - in1[rv * 2 + 1];
        feat[5] = 0.f; feat[6] = 0.f; feat[7] = 0.f;
    }

    // r2-verified cooperative stage of one 32-wide K chunk (hi+lo) into buf.
    auto stage = [&](const f16* __restrict__ Wh, const f16* __restrict__ Wl,
                     const int kst, const int kc, const int buf) {
        #pragma unroll
        for (int i = 0; i < 2; i++) {
            const int c = 2 * w + i;
            const int ophys = c * 1024 + l * 16;
            const int olog  = ophys ^ (((ophys >> 7) & 3) << 4);
            const int row   = olog >> 6;
            const int slot  = (olog >> 4) & 3;
            glds16(Wh + (size_t)row * kst + kc * 32 + slot * 8,
                   (char*)&WH[buf][0] + c * 1024);
            glds16(Wl + (size_t)row * kst + kc * 32 + slot * 8,
                   (char*)&WL[buf][0] + c * 1024);
        }
    };

    // r4-verified per-lane data gather (raw f32, 8 elems).
    auto gather = [&](int kc, float xv[8]) {
        if constexpr (MODE == 2) {
            #pragma unroll
            for (int j = 0; j < 8; j++) xv[j] = (lg == 0) ? feat[j] : 0.f;
        } else {
            const float* src;
            if constexpr (MODE == 0) {
                if (kc < 4)      src = in0 + (size_t)sv  * 128 + kc * 32 + lg * 8;
                else if (kc < 8) src = in0 + (size_t)rv  * 128 + (kc - 4) * 32 + lg * 8;
                else             src = in1 + (size_t)egc * 128 + (kc - 8) * 32 + lg * 8;
            } else {
                if (kc < 4) src = in0 + (size_t)egc * 128 + kc * 32 + lg * 8;
                else        src = in1 + (size_t)egc * 128 + (kc - 4) * 32 + lg * 8;
            }
            const float4 x0 = *(const float4*)src;
            const float4 x1 = *(const float4*)(src + 4);
            xv[0] = x0.x; xv[1] = x0.y; xv[2] = x0.z; xv[3] = x0.w;
            xv[4] = x1.x; xv[5] = x1.y; xv[6] = x1.z; xv[7] = x1.w;
        }
    };

    const f32x4 zero4 = {0.f, 0.f, 0.f, 0.f};
    f32x4 accH[8], accL[8];
    #pragma unroll
    for (int mf = 0; mf < 8; mf++) { accH[mf] = zero4; accL[mf] = zero4; }

    float xnext[8];
    gather(0, xnext);
    stage(W1h, W1l, K1S, 0, 0);          // prologue: fill buffer 0
    int cur = 0;

    // ---------------- layer 1 (one barrier per chunk) ----------------
    for (int kc = 0; kc < NCH1; ++kc) {
        __syncthreads();   // buf[cur] staged (vmcnt drained); prev reads done
        if (kc + 1 < NCH1) stage(W1h, W1l, K1S, kc + 1, cur ^ 1);
        else               stage(W2h, W2l, 128,  0,      cur ^ 1);   // L2 ch0
        union { f16 h[8]; f16x8 v; } XH, XL;
        #pragma unroll
        for (int j = 0; j < 8; j++) {
            const f16 h = (f16)xnext[j];
            XH.h[j] = h;
            XL.h[j] = (f16)((xnext[j] - (float)h) * 2048.f);
        }
        if (kc + 1 < NCH1) gather(kc + 1, xnext);   // prefetch next chunk
        const char* bh = (const char*)&WH[cur][0];
        const char* bl = (const char*)&WL[cur][0];
        #pragma unroll
        for (int mf = 0; mf < 8; mf++) {
            const int off = (mf * 16 + lr) * 64 + (swz << 4);
            const f16x8 wh = *(const f16x8*)(bh + off);
            const f16x8 wl = *(const f16x8*)(bl + off);
            accH[mf] = __builtin_amdgcn_mfma_f32_16x16x32_f16(XH.v, wh, accH[mf], 0, 0, 0);
            accL[mf] = __builtin_amdgcn_mfma_f32_16x16x32_f16(XL.v, wh, accL[mf], 0, 0, 0);
            accL[mf] = __builtin_amdgcn_mfma_f32_16x16x32_f16(XH.v, wl, accL[mf], 0, 0, 0);
        }
        cur ^= 1;
    }

    // layer-1 epilogue: lane holds h1[edge = lg*4+reg][feat = mf*16+lr].
    // bias+relu+split -> packed Y in wave-private LDS rows (no barrier).
    #pragma unroll
    for (int mf = 0; mf < 8; mf++) {
        const float bb1 = b1[mf * 16 + lr];
        #pragma unroll
        for (int reg = 0; reg < 4; reg++) {
            float v = accH[mf][reg] + accL[mf][reg] * (1.f / 2048.f) + bb1;
            v = fmaxf(v, 0.f);
            const f16 h = (f16)v;
            const f16 lo = (f16)((v - (float)h) * 2048.f);
            Yp[(w * 16 + lg * 4 + reg) * 132 + mf * 16 + lr] = pk2(h, lo);
        }
        accH[mf] = zero4; accL[mf] = zero4;
    }

    // ---------------- layer 2 (one barrier per chunk) ----------------
    for (int kc = 0; kc < 4; ++kc) {
        __syncthreads();   // buf[cur] staged; prev reads done
        if (kc + 1 < 4) stage(W2h, W2l, 128, kc + 1, cur ^ 1);
        union { uint32_t u[8]; } Q;
        const uint32_t* yrow = Yp + (w * 16 + lr) * 132 + kc * 32 + lg * 8;
        *(uint4*)&Q.u[0] = *(const uint4*)(yrow);
        *(uint4*)&Q.u[4] = *(const uint4*)(yrow + 4);
        union { f16 h[8]; f16x8 v; } XH, XL;
        #pragma unroll
        for (int j = 0; j < 8; j++) {
            union { uint32_t u; f16 h[2]; } c; c.u = Q.u[j];
            XH.h[j] = c.h[0];
            XL.h[j] = c.h[1];
        }
        const char* bh = (const char*)&WH[cur][0];
        const char* bl = (const char*)&WL[cur][0];
        #pragma unroll
        for (int mf = 0; mf < 8; mf++) {
            const int off = (mf * 16 + lr) * 64 + (swz << 4);
            const f16x8 wh = *(const f16x8*)(bh + off);
            const f16x8 wl = *(const f16x8*)(bl + off);
            accH[mf] = __builtin_amdgcn_mfma_f32_16x16x32_f16(XH.v, wh, accH[mf], 0, 0, 0);
            accL[mf] = __builtin_amdgcn_mfma_f32_16x16x32_f16(XL.v, wh, accL[mf], 0, 0, 0);
            accL[mf] = __builtin_amdgcn_mfma_f32_16x16x32_f16(XH.v, wl, accL[mf], 0, 0, 0);
        }
        cur ^= 1;
    }

    // layer-2 epilogue (r4-verified): bias+relu+LN+apply+store.
    float vv[8][4];
    float s1[4] = {0, 0, 0, 0}, s2[4] = {0, 0, 0, 0};
    #pragma unroll
    for (int mf = 0; mf < 8; mf++) {
        const float bb2 = b2[mf * 16 + lr];
        #pragma unroll
        for (int reg = 0; reg < 4; reg++) {
            float v = accH[mf][reg] + accL[mf][reg] * (1.f / 2048.f) + bb2;
            v = fmaxf(v, 0.f);
            vv[mf][reg] = v;
            s1[reg] += v; s2[reg] += v * v;
        }
    }
    #pragma unroll
    for (int m = 1; m < 16; m <<= 1) {
        #pragma unroll
        for (int reg = 0; reg < 4; reg++) {
            s1[reg] += __shfl_xor(s1[reg], m);
            s2[reg] += __shfl_xor(s2[reg], m);
        }
    }
    float gg[8], b8[8];
    #pragma unroll
    for (int mf = 0; mf < 8; mf++) {
        gg[mf] = gam[mf * 16 + lr];
        b8[mf] = bet[mf * 16 + lr];
    }

    #pragma unroll
    for (int reg = 0; reg < 4; reg++) {
        const float mu = s1[reg] * (1.f / 128.f);
        const float rs = rsqrtf(fmaxf(s2[reg] * (1.f / 128.f) - mu * mu, 0.f) + 1e-5f);
        const int row = w * 16 + lg * 4 + reg;
        const int idx = base + row;
        if (idx < nrows) {
            if constexpr (MODE == 0) {
                const int rc = receivers[idx];
                #pragma unroll
                for (int mf = 0; mf < 8; mf++) {
                    const float o = gg[mf] * (vv[mf][reg] - mu) * rs + b8[mf];
                    atomicAdd(&aggr[(size_t)rc * 128 + mf * 16 + lr], o); // segsum
                    io[(size_t)idx * 128 + mf * 16 + lr] += o;            // el res
                }
            } else if constexpr (MODE == 1) {
                #pragma unroll
                for (int mf = 0; mf < 8; mf++) {
                    const float o = gg[mf] * (vv[mf][reg] - mu) * rs + b8[mf];
                    io[(size_t)idx * 128 + mf * 16 + lr] += o;            // nl res
                }
            } else {
                #pragma unroll
                for (int mf = 0; mf < 8; mf++) {
                    const float o = gg[mf] * (vv[mf][reg] - mu) * rs + b8[mf];
                    io[(size_t)idx * 128 + mf * 16 + lr] = o;             // el enc
                }
            }
        }
    }
}

// Decoder -> FLOAT32 output, layout [TW, N, TD].
__global__ __launch_bounds__(128) void decode_k(
    const float* __restrict__ nl,
    const float* __restrict__ W1, const float* __restrict__ b1,
    const float* __restrict__ W2, const float* __restrict__ b2,
    float* __restrict__ out)
{
    constexpr int NPB = 16;
    __shared__ __align__(16) float xs[NPB * LNUM];
    __shared__ float hh[NPB * 8];
    const int t = threadIdx.x;
    const int base = blockIdx.x * NPB;
    for (int r = 0; r < NPB; r++) xs[r * LNUM + t] = nl[(base + r) * LNUM + t];
    __syncthreads();
    {
        const int node = t >> 3, j = t & 7;
        float a = b1[j];
        for (int k = 0; k < LNUM; k++) a = fmaf(xs[node * LNUM + k], W1[k * 8 + j], a);
        hh[node * 8 + j] = a / (1.f + expf(-a));
    }
    __syncthreads();
    for (int idx = t; idx < NPB * 10; idx += 128) {
        const int node = idx / 10, c = idx % 10;
        float a = b2[c];
        #pragma unroll
        for (int j = 0; j < 8; j++) a = fmaf(hh[node * 8 + j], W2[j * 10 + c], a);
        const int tt = c >> 1, d = c & 1;
        out[(size_t)tt * (NNODES * 2) + (size_t)(base + node) * 2 + d] =
            a * (float)(tt + 1);
    }
}

__global__ __launch_bounds__(256) void zero_k(float* __restrict__ p, int n)
{
    const int i = blockIdx.x * 256 + threadIdx.x;
    if (i < n) p[i] = 0.f;
}

// ---------------------------------------------------------------------------
extern "C" void kernel_launch(void* const* d_in, const int* in_sizes, int n_in,
                              void* d_out, int out_size, void* d_ws, size_t ws_size,
                              hipStream_t stream) {
    const float* F[34];
    for (int i = 0; i < 34; i++) F[i] = (const float*)d_in[i];
    const int* senders   = (const int*)d_in[4];
    const int* receivers = (const int*)d_in[5];

    const size_t nN = (size_t)NNODES * LNUM;
    const size_t nE = (size_t)NEDGES * LNUM;
    float* nl   = (float*)d_ws;
    float* el   = nl + nN;
    float* aggr = el + nE;
    f16* wb = (f16*)(aggr + nN);
    f16 *eW1h = wb,          *eW1l = eW1h + PE1;
    f16 *eW2h = eW1l + PE1,  *eW2l = eW2h + PE2;
    f16 *nW1h = eW2l + PE2,  *nW1l = nW1h + PN1;
    f16 *nW2h = nW1l + PN1,  *nW2l = nW2h + PN2;
    f16 *qW1h = nW2l + PN2,  *qW1l = qW1h + PQ1;
    f16 *qW2h = qW1l + PQ1,  *qW2l = qW2h + PQ2;

    prep_w_all_k<<<(PTOT + 255) / 256, 256, 0, stream>>>(
        F[18], F[20], F[24], F[26], F[12], F[14], wb);

    encode_nodes_k<<<NNODES / 4, 128, 0, stream>>>(
        F[2], F[3], F[1], F[6], F[7], F[8], F[9], F[10], F[11], nl);

    const int egrid = (NEDGES + 63) / 64;   // 2344
    const int ngrid = (NNODES + 63) / 64;   // 469

    // edge encoder (MFMA, computed features)
    mfma_mlp_k<2, 1, 32><<<egrid, 256, 0, stream>>>(
        F[0], F[2], el, nullptr, senders, receivers,
        qW1h, qW1l, F[13], qW2h, qW2l, F[15], F[16], F[17], NEDGES);

    for (int s = 0; s < NSTEPS; s++) {
        zero_k<<<(NNODES * LNUM + 255) / 256, 256, 0, stream>>>(aggr, NNODES * LNUM);
        mfma_mlp_k<0, 12, 384><<<egrid, 256, 0, stream>>>(
            nl, el, el, aggr, senders, receivers,
            eW1h + (size_t)s * 384 * 128, eW1l + (size_t)s * 384 * 128, F[19] + s * LNUM,
            eW2h + (size_t)s * 128 * 128, eW2l + (size_t)s * 128 * 128, F[21] + s * LNUM,
            F[22] + s * LNUM, F[23] + s * LNUM, NEDGES);
        mfma_mlp_k<1, 8, 256><<<ngrid, 256, 0, stream>>>(
            nl, aggr, nl, nullptr, nullptr, nullptr,
            nW1h + (size_t)s * 256 * 128, nW1l + (size_t)s * 256 * 128, F[25] + s * LNUM,
            nW2h + (size_t)s * 128 * 128, nW2l + (size_t)s * 128 * 128, F[27] + s * LNUM,
            F[28] + s * LNUM, F[29] + s * LNUM, NNODES);
    }

    decode_k<<<NNODES / 16, 128, 0, stream>>>(
        nl, F[30], F[31], F[32], F[33], (float*)d_out);
}